// Round 10
// baseline (320.919 us; speedup 1.0000x reference)
//
#include <hip/hip_runtime.h>
#include <hip/hip_bf16.h>

// Problem constants (fixed by reference): B=4, L=4096, R=8, DV=64
#define BB  4
#define LL  4096
#define RR  8
#define DVV 64

typedef __bf16 bf16x8 __attribute__((ext_vector_type(8)));
typedef __bf16 bf16x4 __attribute__((ext_vector_type(4)));
typedef float  f32x4  __attribute__((ext_vector_type(4)));
typedef int    i32x4  __attribute__((ext_vector_type(4)));

#define LGKM_BARRIER() \
  asm volatile("s_waitcnt lgkmcnt(0)\n\ts_barrier" ::: "memory")

// ---------------------------------------------------------------------------
// Pre-kernel (256 blocks x 256 thr): v[b][m][d] fp32 -> vF fragment-linear
// bf16 MFMA B-fragments (unit = (b, colblk32, dblk16); lane l holds
// V[colblk*32 + (l>>4)*8 + j][dblk*16 + (l&15)], 16B contiguous per lane).
// ---------------------------------------------------------------------------
__global__ __launch_bounds__(256) void prep_kernel(
    const float* __restrict__ v, __bf16* __restrict__ vF) {
  __shared__ __bf16 tl[64][72];
  const int blk = blockIdx.x;         // 256 blocks
  const int b   = blk >> 6;           // 64 tiles per batch
  const int m0  = (blk & 63) << 6;
  const int tid = threadIdx.x;

  const float* vb = v + (((size_t)(b * LL + m0)) << 6);
#pragma unroll
  for (int i = 0; i < 16; ++i) {
    const int idx = (i << 8) + tid;   // m = idx>>6, d = idx&63
    tl[idx & 63][idx >> 6] = (__bf16)vb[idx];
  }
  __syncthreads();

  const int wv = tid >> 6, ln = tid & 63;
#pragma unroll
  for (int i = 0; i < 2; ++i) {
    const int u  = wv + (i << 2);
    const int cb = u >> 2, gg = u & 3;
    const int d  = gg * 16 + (ln & 15);
    const int c  = cb * 32 + ((ln >> 4) << 3);
    const size_t unit = ((size_t)(b * 128 + (m0 >> 5) + cb) << 2) + gg;
    *(bf16x8*)(vF + (unit << 9) + (ln << 3)) = *(const bf16x8*)&tl[d][c];
  }
}

// ---------------------------------------------------------------------------
// Main kernel: 2048 WGs x 512 thr (8 waves), 64.25 KB LDS -> 2 WGs/CU.
// == ROUND-9 BASELINE + ONE CHANGE: 4-stage row-pair score pipeline. ==
//
// Duty-cycle theory (the one mechanism rounds 0-9 never cleanly tested):
// all surviving variants issued attn stores only inside the PV window
// (~35% of WG wall time); score is pure VALU/LDS with zero VMEM, so the
// store pipe idled through it. Effective write BW = duty x 6.3 TB/s =
// 0.35 x 6.3 = 2.2 TB/s -- exactly the measured plateau, invariant under
// store shape/issue-structure changes (r3/4/6/8/9 nulls). Round 5 attacked
// duty cycle via persistence but spilled (cross-block reg carries).
// THIS version: within-WG pipeline, no cross-block state. Score runs in
// 4 stages of 2 rows; each stage's stores (previous row-pair, normalized
// with rv0/rv1 -- 2 carried scalars only) are issued at stage START and
// drain under the stage's pure-VALU score compute (no vmcnt waits there).
// Store window now spans stages 1-3 + pre-PV group = ~75% of WG time, and
// per-CU store demand finally fits under the 24.6 GB/s/CU drain rate.
// Everything else byte-identical to round 9 (score math, pbuf layout,
// PV loop now store-free, osum epilogue). Stores are column-slice (r4
// addresses, dense 1KB, proven equal-null) so each wave reads only its
// OWN pbuf slice for stores -- no new cross-wave hazards.
// Pre-commitment: if this is also null, declare roofline.
// ---------------------------------------------------------------------------
__global__ __launch_bounds__(512, 4) void attn_main(
    const float* __restrict__ ra1, const float* __restrict__ ra2,
    const int* __restrict__ mask, const __bf16* __restrict__ vF,
    float* __restrict__ out, float* __restrict__ attn) {
  __shared__ __bf16 pbuf[8 * 8 * 512];    // 64 KB: [wave][row][col] bf16 e
  __shared__ float  red[8][8];            // [row][wave] partial row sums

  const int wg   = blockIdx.x;            // 0..2047
  const int b    = wg >> 9;               // 512 WGs per batch
  const int row0 = (wg & 511) << 3;       // 8 rows per WG
  const int tid  = threadIdx.x;
  const int wave = tid >> 6;              // 0..7
  const int lane = tid & 63;
  const int W    = wave << 9;             // wave's 512-col chunk

  // ---- one-time: ra2 (8r x 2x4 cols) + mask into registers ----
  const float* r2 = ra2 + (size_t)b * (RR * LL) + W + (lane << 2);
  f32x4 rA[RR], rB[RR];
#pragma unroll
  for (int r = 0; r < RR; ++r) {
    rA[r] = *(const f32x4*)(r2 + r * LL);
    rB[r] = *(const f32x4*)(r2 + r * LL + 256);
  }
  const int* mp = mask + (size_t)b * LL + W + (lane << 2);   // mask [B][1][L]
  const i32x4 mAv = *(const i32x4*)mp;
  const i32x4 mBv = *(const i32x4*)(mp + 256);
  f32x4 mA, mB;
#pragma unroll
  for (int j = 0; j < 4; ++j) {
    mA[j] = mAv[j] ? 1.0f : 0.0f;
    mB[j] = mBv[j] ? 1.0f : 0.0f;
  }

  const float* a_base = ra1 + ((size_t)b * LL + row0) * RR;
  char* const  pw     = (char*)pbuf + (wave << 13);   // wave's 8 KB slice
  float* attn_base    = attn + ((size_t)b * LL + row0) * LL + W + (lane << 2);

  float rv0 = 0.f, rv1 = 0.f;   // rinv of previous row pair (2 carried regs)

  // ---- 4-stage score pipeline: stage st scores rows {2st, 2st+1};
  //      stores of rows {2st-2, 2st-1} drain under this stage's VALU ----
#pragma unroll
  for (int st = 0; st < 4; ++st) {
    if (st > 0) {
      // store previous pair (column-slice, dense 1KB per instruction)
#pragma unroll
      for (int h = 0; h < 2; ++h) {
        const int i   = 2 * (st - 1) + h;
        const float rv = h ? rv1 : rv0;
        const int swz = (i & 7) << 4;
        const bf16x4 qA =
            *(const bf16x4*)(pw + (i << 10) + ((lane << 3) ^ swz));
        const bf16x4 qB =
            *(const bf16x4*)(pw + (i << 10) + (512 + ((lane << 3) ^ swz)));
        f32x4 oA, oB;
#pragma unroll
        for (int j = 0; j < 4; ++j) {
          oA[j] = (float)qA[j] * rv;
          oB[j] = (float)qB[j] * rv;
        }
        *(f32x4*)(attn_base + (size_t)i * LL)       = oA;
        *(f32x4*)(attn_base + (size_t)i * LL + 256) = oB;
      }
      __builtin_amdgcn_sched_barrier(0);   // keep stores ahead of the VALU
    }

    float part[2];
#pragma unroll
    for (int h = 0; h < 2; ++h) {
      const int i = 2 * st + h;
      const float* ap = a_base + i * RR;   // row-uniform -> scalar loads
      f32x4 sA = {0.f, 0.f, 0.f, 0.f}, sB = {0.f, 0.f, 0.f, 0.f};
#pragma unroll
      for (int r = 0; r < RR; ++r) {
        const float a = ap[r];
#pragma unroll
        for (int j = 0; j < 4; ++j) {
          sA[j] = fmaf(a, rA[r][j], sA[j]);
          sB[j] = fmaf(a, rB[r][j], sB[j]);
        }
      }
      f32x4 eA, eB;
#pragma unroll
      for (int j = 0; j < 4; ++j) {
        eA[j] = __expf(sA[j]) * mA[j];   // |s| <= ~17: exp safe in fp32
        eB[j] = __expf(sB[j]) * mB[j];
      }
      part[h] = ((eA[0] + eA[1]) + (eA[2] + eA[3])) +
                ((eB[0] + eB[1]) + (eB[2] + eB[3]));

      bf16x4 pA, pB;
#pragma unroll
      for (int j = 0; j < 4; ++j) { pA[j] = (__bf16)eA[j]; pB[j] = (__bf16)eB[j]; }
      const int swz = (i & 7) << 4;
      *(bf16x4*)(pw + (i << 10) + ((lane << 3) ^ swz))         = pA;
      *(bf16x4*)(pw + (i << 10) + (512 + ((lane << 3) ^ swz))) = pB;
    }
    // 2 independent butterfly chains, interleaved
#pragma unroll
    for (int s = 1; s < 64; s <<= 1) {
      part[0] += __shfl_xor(part[0], s);
      part[1] += __shfl_xor(part[1], s);
    }
    if (lane == 0) {
      red[2 * st][wave]     = part[0];
      red[2 * st + 1][wave] = part[1];
    }
    LGKM_BARRIER();   // this pair's red ready (lgkm-only: stores in flight)
    {
      const f32x4 r00 = *(const f32x4*)&red[2 * st][0];
      const f32x4 r01 = *(const f32x4*)&red[2 * st][4];
      const f32x4 r10 = *(const f32x4*)&red[2 * st + 1][0];
      const f32x4 r11 = *(const f32x4*)&red[2 * st + 1][4];
      rv0 = 1.0f / (((r00[0] + r00[1]) + (r00[2] + r00[3])) +
                    ((r01[0] + r01[1]) + (r01[2] + r01[3])));
      rv1 = 1.0f / (((r10[0] + r10[1]) + (r10[2] + r10[3])) +
                    ((r11[0] + r11[1]) + (r11[2] + r11[3])));
    }
  }

  // ---- store last pair (rows 6,7) before PV's first load enters FIFO ----
#pragma unroll
  for (int h = 0; h < 2; ++h) {
    const int i    = 6 + h;
    const float rv = h ? rv1 : rv0;
    const int swz  = (i & 7) << 4;
    const bf16x4 qA = *(const bf16x4*)(pw + (i << 10) + ((lane << 3) ^ swz));
    const bf16x4 qB =
        *(const bf16x4*)(pw + (i << 10) + (512 + ((lane << 3) ^ swz)));
    f32x4 oA, oB;
#pragma unroll
    for (int j = 0; j < 4; ++j) {
      oA[j] = (float)qA[j] * rv;
      oB[j] = (float)qB[j] * rv;
    }
    *(f32x4*)(attn_base + (size_t)i * LL)       = oA;
    *(f32x4*)(attn_base + (size_t)i * LL + 256) = oB;
  }
  __builtin_amdgcn_sched_barrier(0);

  // ---- PV MFMA: pure loads + MFMA (no stores in the loop) ----
  const int lrow = lane & 15, kg = lane >> 4;
  const int lr8  = lrow & 7;              // A rows 8-15 duplicate rows 0-7
  f32x4 acc[4];
#pragma unroll
  for (int g = 0; g < 4; ++g) acc[g] = (f32x4){0.f, 0.f, 0.f, 0.f};
  const __bf16* vFb = vF + ((size_t)b << 18);
#pragma unroll
  for (int t = 0; t < 16; ++t) {
    const bf16x8 af = *(const bf16x8*)(
        pw + (lr8 << 10) + (((t << 6) + (kg << 4)) ^ (lr8 << 4)));
    const __bf16* vblk =
        vFb + ((size_t)((wave << 4) + t) << 11) + (lane << 3);
#pragma unroll
    for (int g = 0; g < 4; ++g) {
      const bf16x8 bf = *(const bf16x8*)(vblk + (g << 9));
      acc[g] =
          __builtin_amdgcn_mfma_f32_16x16x32_bf16(af, bf, acc[g], 0, 0, 0);
    }
  }

  // ---- cross-wave O reduction: reuse pbuf; lgkm-only barriers keep any
  //      remaining attn stores in flight ----
  LGKM_BARRIER();
  float* osum = (float*)pbuf;   // [8 waves][8 rows][64 d] fp32 = 16 KB
  // C/D layout: row = kg*4 + ii (valid rows 0-7 -> kg<2), col = g*16 + lrow
  if (kg < 2) {
#pragma unroll
    for (int g = 0; g < 4; ++g)
#pragma unroll
      for (int ii = 0; ii < 4; ++ii)
        osum[(wave * 8 + kg * 4 + ii) * 64 + g * 16 + lrow] = acc[g][ii];
  }
  LGKM_BARRIER();

  if (tid < 128) {
    const int orow = tid >> 4;          // 0..7
    const int d    = (tid & 15) << 2;   // 0,4,..,60
    f32x4 o = {0.f, 0.f, 0.f, 0.f};
#pragma unroll
    for (int w = 0; w < 8; ++w) {
      const f32x4 rr = *(const f32x4*)(osum + ((w * 8 + orow) << 6) + d);
#pragma unroll
      for (int j = 0; j < 4; ++j) o[j] += rr[j];
    }
    float rt = 0.f;
#pragma unroll
    for (int w = 0; w < 8; ++w) rt += red[orow][w];
    const float rinv_o = 1.0f / rt;   // deferred normalization of PV
#pragma unroll
    for (int j = 0; j < 4; ++j) o[j] *= rinv_o;
    *(f32x4*)(out + ((size_t)b * LL + row0 + orow) * DVV + d) = o;
  }
}

extern "C" void kernel_launch(void* const* d_in, const int* in_sizes, int n_in,
                              void* d_out, int out_size, void* d_ws,
                              size_t ws_size, hipStream_t stream) {
  (void)in_sizes; (void)n_in; (void)out_size; (void)ws_size;
  const float* v    = (const float*)d_in[0];
  const int*   mask = (const int*)d_in[1];
  const float* ra1  = (const float*)d_in[2];
  const float* ra2  = (const float*)d_in[3];
  // d_in[4] = len_q, always 4096 (shapes fixed) -> constants above

  float* out  = (float*)d_out;
  float* attn = out + (size_t)BB * LL * DVV;   // outputs concatenated

  __bf16* vF = (__bf16*)d_ws;                  // 2 MB fragment-linear V

  hipLaunchKernelGGL(prep_kernel, dim3(BB * (LL / 64)), dim3(256), 0, stream,
                     v, vF);
  hipLaunchKernelGGL(attn_main, dim3(BB * LL / 8), dim3(512), 0, stream,
                     ra1, ra2, mask, vF, out, attn);
}